// Round 1
// baseline (102.873 us; speedup 1.0000x reference)
//
#include <hip/hip_runtime.h>
#include <hip/hip_bf16.h>

#define N_NODES 4096
#define N_PER   128
#define D_DIM   64

// Projection: p1[n][d] = b[d] + sum_k x[n][k]*W[d][k]
//             p2[n][d] =        sum_k x[n][k]*W[d][64+k]
// One wave per node, lane = d.
__global__ void proj_kernel(const float* __restrict__ x,
                            const float* __restrict__ W,
                            const float* __restrict__ b,
                            float* __restrict__ p1,
                            float* __restrict__ p2) {
    int n = blockIdx.x * 4 + (threadIdx.x >> 6);
    int d = threadIdx.x & 63;
    if (n >= N_NODES) return;
    const float* xr = x + (size_t)n * D_DIM;
    const float* w  = W + (size_t)d * (2 * D_DIM);
    float a1 = b[d];
    float a2 = 0.0f;
#pragma unroll
    for (int k = 0; k < D_DIM; ++k) {
        float xv = xr[k];
        a1 += xv * w[k];
        a2 += xv * w[D_DIM + k];
    }
    p1[(size_t)n * D_DIM + d] = a1;
    p2[(size_t)n * D_DIM + d] = a2;
}

// Scatter edge_attr rows into dense adj: out[g, r, c, d] += attr[e, d]
// One wave (64 lanes) per edge; lane = d; 4 edges per 256-thread block.
__global__ void scatter_edges(const int* __restrict__ src,
                              const int* __restrict__ dst,
                              const float* __restrict__ attr,
                              float* __restrict__ out,
                              int M) {
    int e = blockIdx.x * 4 + (threadIdx.x >> 6);
    int d = threadIdx.x & 63;
    if (e >= M) return;
    int s = src[e];
    int t = dst[e];
    int g = s >> 7;          // graph id (N_PER = 128)
    int r = s & 127;         // row within graph
    int c = t & 127;         // col within graph
    size_t addr = ((((size_t)g * N_PER + r) * N_PER + c) << 6) + d;
    atomicAdd(out + addr, attr[(size_t)e * D_DIM + d]);
}

// Scatter projected token features: out[g, r, c, d] += p1[s][d] + p2[t][d]
__global__ void scatter_tokens(const int* __restrict__ src,
                               const int* __restrict__ dst,
                               const float* __restrict__ p1,
                               const float* __restrict__ p2,
                               float* __restrict__ out,
                               int M) {
    int e = blockIdx.x * 4 + (threadIdx.x >> 6);
    int d = threadIdx.x & 63;
    if (e >= M) return;
    int s = src[e];
    int t = dst[e];
    int g = s >> 7;
    int r = s & 127;
    int c = t & 127;
    float v = p1[(size_t)s * D_DIM + d] + p2[(size_t)t * D_DIM + d];
    size_t addr = ((((size_t)g * N_PER + r) * N_PER + c) << 6) + d;
    atomicAdd(out + addr, v);
}

extern "C" void kernel_launch(void* const* d_in, const int* in_sizes, int n_in,
                              void* d_out, int out_size, void* d_ws, size_t ws_size,
                              hipStream_t stream) {
    const float* x          = (const float*)d_in[0];
    const int*   edge_index = (const int*)d_in[1];
    const float* edge_attr  = (const float*)d_in[2];
    // d_in[3] = batch (unused: indices are intra-graph with N_PER=128 stride)
    const int*   token_index = (const int*)d_in[4];
    const float* W          = (const float*)d_in[5];
    const float* b          = (const float*)d_in[6];

    const int E = in_sizes[1] / 2;   // 131072
    const int T = in_sizes[4] / 2;   // 131072

    float* out = (float*)d_out;
    float* p1 = (float*)d_ws;
    float* p2 = p1 + (size_t)N_NODES * D_DIM;

    // Zero the dense output (scatter-add target).
    hipMemsetAsync(d_out, 0, (size_t)out_size * sizeof(float), stream);

    // Projection: 4096 nodes, 4 nodes / 256-thread block.
    proj_kernel<<<N_NODES / 4, 256, 0, stream>>>(x, W, b, p1, p2);

    // Edge scatter: 4 edges / block.
    scatter_edges<<<(E + 3) / 4, 256, 0, stream>>>(
        edge_index, edge_index + E, edge_attr, out, E);

    // Token scatter.
    scatter_tokens<<<(T + 3) / 4, 256, 0, stream>>>(
        token_index, token_index + T, p1, p2, out, T);
}